// Round 8
// baseline (448.467 us; speedup 1.0000x reference)
//
#include <hip/hip_runtime.h>
#include <stdint.h>

// DSA sparse attention, MI355X. T=512 tok, H=128 heads, K=512 selected keys,
// C=576 (512 lora + 64 rope), S=8192 cache rows.
// Pipeline: kv->bf16, rope copy (SCALE folded), q_lat GEMM, scores GEMM,
// row softmax (writes A-frag-swizzled P2), attn GEMM, out GEMM.
// GEMMs: 128x128 tile, BK=32, 4 waves x (4x4 of 16x16x32 bf16 MFMA), m90/m92:
// A[m=lane&15][k=quad*8+j], B[n=lane&15][k=quad*8+j], D col=lane&15 row=quad*4+reg.
//
// R1->R2: attn 32-way LDS write conflicts fixed.         (475->403 us)
// R2->R3: XCD swizzle + global_load_lds staging.          (403->400)
// R3->R4: transpose bank tuning - NEUTRAL.                (397)
// R4->R5: direct-A from swizzled P2 + dbuf DMA - NEUTRAL. (393)
// R5->R7: fp8 V storage - FAILED accuracy (3.4e-3 > 2.6e-3). fp8 is dead.
// R7->R8: the attn binder is __syncthreads() = s_waitcnt vmcnt(0) draining
//      the gather DMA every ks (<1 iter of latency hiding vs ~600-900cyc
//      scattered L3 reads). Gather now goes global->VGPR (barriers don't
//      drain VGPR loads; the vmcnt wait lands before the dependent ds_write)
//      with prefetch distance 2, St filled from regs, 2 lgkm-only barriers/ks.

#define SCALE 0.041666666666666664f  // (512+64)^-0.5

typedef __bf16 bf16x8 __attribute__((ext_vector_type(8)));
typedef float floatx4 __attribute__((ext_vector_type(4)));

static __device__ __forceinline__ unsigned short f2bf(float f) {
  unsigned int u = __builtin_bit_cast(unsigned int, f);
  u += 0x7FFF + ((u >> 16) & 1);  // RNE
  return (unsigned short)(u >> 16);
}
static __device__ __forceinline__ float bf2f(unsigned short h) {
  unsigned int u = ((unsigned int)h) << 16;
  return __builtin_bit_cast(float, u);
}
static __device__ __forceinline__ unsigned int pack2(float lo, float hi) {
  return (unsigned int)f2bf(lo) | ((unsigned int)f2bf(hi) << 16);
}
// async global->LDS, 16B per lane; LDS dest = wave base + lane*16 (m97 pattern)
static __device__ __forceinline__ void ldsdma16(const void* g, void* l) {
  __builtin_amdgcn_global_load_lds(
      (const __attribute__((address_space(1))) void*)g,
      (__attribute__((address_space(3))) void*)l, 16, 0, 0);
}
// stage 8 fp32 -> 8 bf16 into LDS (16B aligned)
static __device__ __forceinline__ void stage8_f32(const float* __restrict__ src,
                                                  unsigned short* dst) {
  const float4* s4 = reinterpret_cast<const float4*>(src);
  float4 v0 = s4[0], v1 = s4[1];
  uint4 o;
  o.x = pack2(v0.x, v0.y); o.y = pack2(v0.z, v0.w);
  o.z = pack2(v1.x, v1.y); o.w = pack2(v1.z, v1.w);
  *reinterpret_cast<uint4*>(dst) = o;
}

static __device__ __forceinline__ void mfma_4x4(const unsigned short* As,
                                                const unsigned short* Bs,
                                                int wm, int wn, int l15, int quad,
                                                floatx4 acc[4][4]) {
  bf16x8 af[4], bfr[4];
#pragma unroll
  for (int i = 0; i < 4; ++i)
    af[i] = *reinterpret_cast<const bf16x8*>(&As[(wm + i * 16 + l15) * 32 + quad * 8]);
#pragma unroll
  for (int j = 0; j < 4; ++j)
    bfr[j] = *reinterpret_cast<const bf16x8*>(&Bs[(wn + j * 16 + l15) * 32 + quad * 8]);
#pragma unroll
  for (int i = 0; i < 4; ++i)
#pragma unroll
    for (int j = 0; j < 4; ++j)
      acc[i][j] = __builtin_amdgcn_mfma_f32_16x16x32_bf16(af[i], bfr[j], acc[i][j], 0, 0, 0);
}

// ---------------- K0a: kv_cache fp32 -> bf16 ----------------
__global__ void kv_convert(const float* __restrict__ kv, unsigned short* __restrict__ kvb) {
  int i = blockIdx.x * 256 + threadIdx.x;  // per 4 elems, grid sized exactly
  float4 v = reinterpret_cast<const float4*>(kv)[i];
  ushort4 o;
  o.x = f2bf(v.x); o.y = f2bf(v.y); o.z = f2bf(v.z); o.w = f2bf(v.w);
  reinterpret_cast<ushort4*>(kvb)[i] = o;
}

// ---------------- K0b: q_rope * SCALE -> q_concat[..., 512:576] ----------------
__global__ void rope_copy(const float* __restrict__ q, unsigned short* __restrict__ qc) {
  int i = blockIdx.x * 256 + threadIdx.x;  // 512*128*64 total
  int r = i & 63;
  int th = i >> 6;  // t*128 + h
  qc[(size_t)th * 576 + 512 + r] = f2bf(q[(size_t)th * 192 + 128 + r] * SCALE);
}

// ---------------- K1: q_lat = per-head (T x 128) @ (512 x 128)^T, * SCALE ----------------
// grid (128, 16): x = h so all 16 tile-blocks of one head share an XCD L2.
__global__ __launch_bounds__(256) void qlat_gemm(const float* __restrict__ q,
                                                 const float* __restrict__ kb,
                                                 unsigned short* __restrict__ qc) {
  const int h = blockIdx.x;
  const int tm = (blockIdx.y & 3) * 128;   // token tile
  const int tn = (blockIdx.y >> 2) * 128;  // lora-dim tile
  __shared__ __align__(16) unsigned short As[128 * 32];
  __shared__ __align__(16) unsigned short Bs[128 * 32];
  const int tid = threadIdx.x;
  const int lane = tid & 63, wave = tid >> 6;
  const int wm = (wave & 1) * 64, wn = (wave >> 1) * 64;
  const int l15 = lane & 15, quad = lane >> 4;
  const int r0 = tid >> 2, cg = tid & 3;
  const float* a0 = q + ((size_t)(tm + r0) * 128 + h) * 192 + cg * 8;
  const float* a1 = q + ((size_t)(tm + r0 + 64) * 128 + h) * 192 + cg * 8;
  const float* b0 = kb + ((size_t)h * 512 + tn + r0) * 128 + cg * 8;
  const float* b1 = b0 + (size_t)64 * 128;
  floatx4 acc[4][4] = {};
  for (int ks = 0; ks < 4; ++ks) {  // contraction 128 = 4*32
    stage8_f32(a0 + ks * 32, &As[tid * 8]);
    stage8_f32(a1 + ks * 32, &As[2048 + tid * 8]);
    stage8_f32(b0 + ks * 32, &Bs[tid * 8]);
    stage8_f32(b1 + ks * 32, &Bs[2048 + tid * 8]);
    __syncthreads();
    mfma_4x4(As, Bs, wm, wn, l15, quad, acc);
    __syncthreads();
  }
#pragma unroll
  for (int i = 0; i < 4; ++i) {
    const int row = wm + i * 16 + quad * 4;  // token-local
#pragma unroll
    for (int j = 0; j < 4; ++j) {
      const int col = wn + j * 16 + l15;  // lora-dim-local
#pragma unroll
      for (int r = 0; r < 4; ++r) {
        const int t = tm + row + r;
        qc[((size_t)t * 128 + h) * 576 + tn + col] = f2bf(acc[i][j][r] * SCALE);
      }
    }
  }
}

// ---------------- K2: scores (128h x 128key tile) = Qc @ KVsel^T (bf16) ----------------
// grid (512, 4): x = t so the 4 key-tile blocks sharing A[t] share an XCD L2.
__global__ __launch_bounds__(256) void scores_gemm(const unsigned short* __restrict__ qc,
                                                   const unsigned short* __restrict__ kvb,
                                                   const int* __restrict__ topk,
                                                   unsigned short* __restrict__ P) {
  const int t = blockIdx.x;
  const int tn = blockIdx.y * 128;  // key tile
  __shared__ __align__(16) unsigned short As[128 * 32];
  __shared__ __align__(16) unsigned short Bs[128 * 32];
  const int tid = threadIdx.x;
  const int lane = tid & 63, wave = tid >> 6;
  const int wm = (wave & 1) * 64, wn = (wave >> 1) * 64;
  const int l15 = lane & 15, quad = lane >> 4;
  const int r0 = tid >> 2, cg = tid & 3;
  const unsigned short* a0 = qc + ((size_t)t * 128 + r0) * 576 + cg * 8;
  const unsigned short* a1 = a0 + (size_t)64 * 576;
  const int idx0 = topk[t * 512 + tn + r0];
  const int idx1 = topk[t * 512 + tn + r0 + 64];
  const unsigned short* b0 = kvb + (size_t)idx0 * 576 + cg * 8;
  const unsigned short* b1 = kvb + (size_t)idx1 * 576 + cg * 8;
  floatx4 acc[4][4] = {};
  for (int ks = 0; ks < 18; ++ks) {  // contraction 576 = 18*32
    ldsdma16(a0 + ks * 32, &As[tid * 8]);
    ldsdma16(a1 + ks * 32, &As[2048 + tid * 8]);
    ldsdma16(b0 + ks * 32, &Bs[tid * 8]);
    ldsdma16(b1 + ks * 32, &Bs[2048 + tid * 8]);
    __syncthreads();
    mfma_4x4(As, Bs, wm, wn, l15, quad, acc);
    __syncthreads();
  }
#pragma unroll
  for (int i = 0; i < 4; ++i) {
    const int row = wm + i * 16 + quad * 4;  // head
#pragma unroll
    for (int j = 0; j < 4; ++j) {
      const int col = tn + wn + j * 16 + l15;  // key
#pragma unroll
      for (int r = 0; r < 4; ++r)
        P[((size_t)t * 128 + row + r) * 512 + col] = f2bf(acc[i][j][r]);
    }
  }
}

// ---------------- K3: softmax rows of 512; writes P2 in A-fragment order ----------------
// P2 layout: [t][ks=key>>5][h][key&31]; lane l holds keys 8l..8l+7.
__global__ __launch_bounds__(256) void softmax_rows(const unsigned short* __restrict__ Pin,
                                                    unsigned short* __restrict__ P2) {
  const int row = blockIdx.x * 4 + (threadIdx.x >> 6);  // t*128 + h
  const int t = row >> 7, h = row & 127;
  const int lane = threadIdx.x & 63;
  const unsigned short* rp = Pin + (size_t)row * 512 + lane * 8;
  uint4 raw = *reinterpret_cast<const uint4*>(rp);
  unsigned int w[4] = {raw.x, raw.y, raw.z, raw.w};
  float f[8];
  float mx = -1e30f;
#pragma unroll
  for (int i = 0; i < 8; ++i) {
    f[i] = bf2f((unsigned short)((w[i >> 1] >> ((i & 1) * 16)) & 0xFFFF));
    mx = fmaxf(mx, f[i]);
  }
#pragma unroll
  for (int off = 32; off; off >>= 1) mx = fmaxf(mx, __shfl_xor(mx, off, 64));
  float s = 0.f;
#pragma unroll
  for (int i = 0; i < 8; ++i) { f[i] = __expf(f[i] - mx); s += f[i]; }
#pragma unroll
  for (int off = 32; off; off >>= 1) s += __shfl_xor(s, off, 64);
  const float inv = 1.0f / s;
  uint4 o;
  o.x = pack2(f[0] * inv, f[1] * inv);
  o.y = pack2(f[2] * inv, f[3] * inv);
  o.z = pack2(f[4] * inv, f[5] * inv);
  o.w = pack2(f[6] * inv, f[7] * inv);
  unsigned short* wp =
      P2 + (((size_t)t * 16 + (lane >> 2)) * 128 + h) * 32 + (lane & 3) * 8;
  *reinterpret_cast<uint4*>(wp) = o;
}

// ---------------- K4: attn_lat (128h x 128c tile) = P @ KVsel[:, :512] ----------------
// grid (512, 4): x = t. A-fragments direct from swizzled P2 (register prefetch).
// KV gather goes global->VGPR (prefetch distance 2) so per-ks barriers wait
// lgkm only (VGPR loads don't drain at s_barrier); St filled from regs.
// Transpose St[32key][128c] -> Bs[128c][32key] (stride 40; writes/reads at
// the 8-word/bank floor).
#define BSTRIDE 40
__global__ __launch_bounds__(256) void attn_gemm(const unsigned short* __restrict__ P2,
                                                 const unsigned short* __restrict__ kvb,
                                                 const int* __restrict__ topk,
                                                 unsigned short* __restrict__ alat) {
  const int t = blockIdx.x;
  const int tn = blockIdx.y * 128;  // c-dim tile
  __shared__ __align__(16) unsigned short St[32 * 128];
  __shared__ __align__(16) unsigned short Bs[128 * BSTRIDE];
  const int tid = threadIdx.x;
  const int lane = tid & 63, wave = tid >> 6;
  const int wm = (wave & 1) * 64, wn = (wave >> 1) * 64;
  const int l15 = lane & 15, quad = lane >> 4;
  const int key0 = tid >> 4;  // 0..15 (and +16)
  const int cs = tid & 15;    // 16B slot in the 256B c-chunk
  const int kgT = tid & 3;    // transpose: key-group 0..3 (8 keys)
  const int cp = tid >> 2;    // transpose: c-pair 0..63
  const int* tkrow = topk + t * 512;
  const unsigned short* a_base =
      P2 + ((size_t)t * 16 * 128 + wm + l15) * 32 + quad * 8;
  floatx4 acc[4][4] = {};
  bf16x8 a_cur[4], a_nxt[4];
  uint4 gv[2][2];
  {  // preload: gathers for ks=0,1 into regs; A(0) into regs
    int i0 = tkrow[key0], i1 = tkrow[16 + key0];
    gv[0][0] = *reinterpret_cast<const uint4*>(kvb + (size_t)i0 * 576 + tn + cs * 8);
    gv[0][1] = *reinterpret_cast<const uint4*>(kvb + (size_t)i1 * 576 + tn + cs * 8);
    i0 = tkrow[32 + key0]; i1 = tkrow[48 + key0];
    gv[1][0] = *reinterpret_cast<const uint4*>(kvb + (size_t)i0 * 576 + tn + cs * 8);
    gv[1][1] = *reinterpret_cast<const uint4*>(kvb + (size_t)i1 * 576 + tn + cs * 8);
#pragma unroll
    for (int i = 0; i < 4; ++i)
      a_cur[i] = *reinterpret_cast<const bf16x8*>(a_base + (size_t)i * 16 * 32);
  }
  for (int ks = 0; ks < 16; ++ks) {
    const int sel = ks & 1;
    // St fill from regs (vmcnt wait lands HERE, 2 iterations after issue)
    *reinterpret_cast<uint4*>(&St[key0 * 128 + cs * 8]) = gv[sel][0];
    *reinterpret_cast<uint4*>(&St[(key0 + 16) * 128 + cs * 8]) = gv[sel][1];
    // issue gather for ks+2 (reuses gv[sel]; in-order issue preserves WAR)
    if (ks < 14) {
      const int i0 = tkrow[(ks + 2) * 32 + key0];
      const int i1 = tkrow[(ks + 2) * 32 + 16 + key0];
      gv[sel][0] = *reinterpret_cast<const uint4*>(kvb + (size_t)i0 * 576 + tn + cs * 8);
      gv[sel][1] = *reinterpret_cast<const uint4*>(kvb + (size_t)i1 * 576 + tn + cs * 8);
    }
    __syncthreads();  // St ready (lgkm only; no DMA outstanding)
    // transpose: thread (cp, kgT) reads 8 c-pair words, writes 2 b128 rows
    unsigned int w[8];
#pragma unroll
    for (int i = 0; i < 8; ++i)
      w[i] = *reinterpret_cast<const unsigned int*>(&St[(kgT * 8 + i) * 128 + cp * 2]);
    unsigned short r0[8], r1[8];
#pragma unroll
    for (int i = 0; i < 8; ++i) {
      r0[i] = (unsigned short)(w[i] & 0xFFFF);
      r1[i] = (unsigned short)(w[i] >> 16);
    }
    *reinterpret_cast<uint4*>(&Bs[(2 * cp) * BSTRIDE + kgT * 8]) =
        *reinterpret_cast<const uint4*>(r0);
    *reinterpret_cast<uint4*>(&Bs[(2 * cp + 1) * BSTRIDE + kgT * 8]) =
        *reinterpret_cast<const uint4*>(r1);
    if (ks < 15) {
#pragma unroll
      for (int i = 0; i < 4; ++i)
        a_nxt[i] = *reinterpret_cast<const bf16x8*>(
            a_base + ((size_t)(ks + 1) * 128 + i * 16) * 32);
    }
    __syncthreads();  // Bs ready
    bf16x8 bfr[4];
#pragma unroll
    for (int j = 0; j < 4; ++j)
      bfr[j] = *reinterpret_cast<const bf16x8*>(
          &Bs[(wn + j * 16 + l15) * BSTRIDE + quad * 8]);
#pragma unroll
    for (int i = 0; i < 4; ++i)
#pragma unroll
      for (int j = 0; j < 4; ++j)
        acc[i][j] =
            __builtin_amdgcn_mfma_f32_16x16x32_bf16(a_cur[i], bfr[j], acc[i][j], 0, 0, 0);
#pragma unroll
    for (int i = 0; i < 4; ++i) a_cur[i] = a_nxt[i];
  }
  // write attn_lat in (H, T, 512) layout for K5's contiguous A reads
#pragma unroll
  for (int i = 0; i < 4; ++i) {
    const int row = wm + i * 16 + quad * 4;  // head
#pragma unroll
    for (int j = 0; j < 4; ++j) {
      const int col = tn + wn + j * 16 + l15;  // c
#pragma unroll
      for (int r = 0; r < 4; ++r)
        alat[((size_t)(row + r) * 512 + t) * 512 + col] = f2bf(acc[i][j][r]);
    }
  }
}

// ---------------- K5: out (128t x 128v tile) = attn_lat[h] @ v_b[h]^T ----------------
// grid (128, 4): x = h so the 4 token-tile blocks sharing B[h] share an XCD L2.
__global__ __launch_bounds__(256) void out_gemm(const unsigned short* __restrict__ alat,
                                                const float* __restrict__ vb,
                                                float* __restrict__ out) {
  const int h = blockIdx.x;
  const int tm = blockIdx.y * 128;  // token tile
  __shared__ __align__(16) unsigned short As[128 * 32];
  __shared__ __align__(16) unsigned short Bs[128 * 32];
  const int tid = threadIdx.x;
  const int lane = tid & 63, wave = tid >> 6;
  const int wm = (wave & 1) * 64, wn = (wave >> 1) * 64;
  const int l15 = lane & 15, quad = lane >> 4;
  const int r0 = tid >> 2, cg = tid & 3;
  const unsigned short* a0 = alat + ((size_t)h * 512 + tm + r0) * 512 + cg * 8;
  const unsigned short* a1 = a0 + (size_t)64 * 512;
  const float* b0 = vb + ((size_t)h * 128 + r0) * 512 + cg * 8;
  const float* b1 = b0 + (size_t)64 * 512;
  floatx4 acc[4][4] = {};
  for (int ks = 0; ks < 16; ++ks) {  // contraction 512 = 16*32
    ldsdma16(a0 + ks * 32, &As[tid * 8]);
    ldsdma16(a1 + ks * 32, &As[2048 + tid * 8]);
    stage8_f32(b0 + ks * 32, &Bs[tid * 8]);
    stage8_f32(b1 + ks * 32, &Bs[2048 + tid * 8]);
    __syncthreads();
    mfma_4x4(As, Bs, wm, wn, l15, quad, acc);
    __syncthreads();
  }
#pragma unroll
  for (int i = 0; i < 4; ++i) {
    const int row = wm + i * 16 + quad * 4;  // token-local
#pragma unroll
    for (int j = 0; j < 4; ++j) {
      const int col = wn + j * 16 + l15;  // v
#pragma unroll
      for (int r = 0; r < 4; ++r) {
        const int t = tm + row + r;
        out[((size_t)t * 128 + h) * 128 + col] = acc[i][j][r];
      }
    }
  }
}

extern "C" void kernel_launch(void* const* d_in, const int* in_sizes, int n_in,
                              void* d_out, int out_size, void* d_ws, size_t ws_size,
                              hipStream_t stream) {
  const float* q = (const float*)d_in[0];         // (512,128,192)
  const float* kv = (const float*)d_in[1];        // (8192,576)
  const int* topk = (const int*)d_in[2];          // (512,512)
  const float* kb = (const float*)d_in[3];        // (128,512,128)
  const float* vb = (const float*)d_in[4];        // (128,128,512)
  float* out = (float*)d_out;                     // (512,128,128)

  char* ws = (char*)d_ws;
  unsigned short* kvb = (unsigned short*)ws;                       // 9,437,184 B
  unsigned short* qc = (unsigned short*)(ws + 9437184);            // 75,497,472 B
  unsigned short* P = (unsigned short*)(ws + 9437184 + 75497472);  // 67,108,864 B
  // lifetime reuse: P2 -> dead qc region; alat -> dead P region. total 152MB
  unsigned short* P2 = qc;
  unsigned short* alat = P;

  kv_convert<<<dim3(4608), dim3(256), 0, stream>>>(kv, kvb);
  rope_copy<<<dim3(16384), dim3(256), 0, stream>>>(q, qc);
  qlat_gemm<<<dim3(128, 16), dim3(256), 0, stream>>>(q, kb, qc);
  scores_gemm<<<dim3(512, 4), dim3(256), 0, stream>>>(qc, kvb, topk, P);
  softmax_rows<<<dim3(16384), dim3(256), 0, stream>>>(P, P2);
  attn_gemm<<<dim3(512, 4), dim3(256), 0, stream>>>(P2, kvb, topk, alat);
  out_gemm<<<dim3(128, 4), dim3(256), 0, stream>>>(alat, vb, out);
}